// Round 2
// baseline (2074.545 us; speedup 1.0000x reference)
//
#include <hip/hip_runtime.h>

// ---------------------------------------------------------------------------
// Earth-specific transformer block (Pangu/swin style) for MI355X gfx950.
// DIM=192, HEADS=6 (d=32), RES=(8,96,180), WIN=(2,6,12), SHIFT=(1,3,6), MLP=4x
// L=138240 tokens, windows: 15 lon-batches x 64 windows x 144 tokens.
// All GEMMs in bf16 MFMA (16x16x32), fp32 accumulate. Output fp32.
// R1: GEMM rewritten — weight tile staged in LDS per 192-wide K-chunk,
//     wave tile 64x96 (24 MFMA / 6 ds_read_b128 / 4 global loads per k-step).
// ---------------------------------------------------------------------------

typedef __attribute__((ext_vector_type(8))) short short8;
typedef __attribute__((ext_vector_type(4))) float floatx4;
typedef unsigned short bfu;   // raw bf16 bits

__device__ __forceinline__ bfu f2bf(float f) {
  unsigned int u = __builtin_bit_cast(unsigned int, f);
  u += 0x7fffu + ((u >> 16) & 1u);        // round-to-nearest-even
  return (bfu)(u >> 16);
}
__device__ __forceinline__ float bf2f(bfu s) {
  return __builtin_bit_cast(float, (unsigned int)s << 16);
}

// --- transpose fp32 (K x N) -> bf16 (N x K) --------------------------------
__global__ void wt_kernel(const float* __restrict__ src, bfu* __restrict__ dst,
                          int K, int N) {
  int idx = blockIdx.x * 256 + threadIdx.x;
  if (idx >= K * N) return;
  int k = idx / N, n = idx % N;
  dst[(size_t)n * K + k] = f2bf(src[idx]);
}

// --- precompute bias[h][w][n][m] (bf16) from bias_table via EPI ------------
__global__ void bias_prep_kernel(const float* __restrict__ table,
                                 bfu* __restrict__ out) {
  size_t idx = (size_t)blockIdx.x * 256 + threadIdx.x;
  if (idx >= 7962624) return;                    // 6*64*144*144
  int m = (int)(idx % 144);
  int n = (int)((idx / 144) % 144);
  int w = (int)((idx / 20736) % 64);
  int h = (int)(idx / 1327104);
  int p1 = n / 72, l1 = (n / 12) % 6, o1 = n % 12;
  int p2 = m / 72, l2 = (m / 12) % 6, o2 = m % 12;
  int ep = 828 * (p1 + 2 * p2) + 23 * (l1 + 6 * l2) + (o1 - o2 + 11);
  out[idx] = f2bf(table[(size_t)(ep * 64 + w) * 6 + h]);
}

// --- LN1 + roll(-shift) + window-partition gather -> bf16 A1 ---------------
__global__ __launch_bounds__(256) void ln1_kernel(
    const float* __restrict__ x, const float* __restrict__ g,
    const float* __restrict__ be, bfu* __restrict__ A1) {
  int wv = threadIdx.x >> 6, lane = threadIdx.x & 63;
  int r = blockIdx.x * 4 + wv;
  int n = r % 144, w = (r / 144) & 63, bb = r / 9216;
  int ip = w >> 4, il = w & 15;
  int p1 = n / 72, rem = n % 72, l1 = rem / 12, o1 = rem % 12;
  int pl = ip * 2 + p1 + 1;   if (pl >= 8) pl -= 8;     // rolled pos + shift
  int lat = il * 6 + l1 + 3;  if (lat >= 96) lat -= 96;
  int lon = bb * 12 + o1 + 6; if (lon >= 180) lon -= 180;
  size_t t = (size_t)(pl * 96 + lat) * 180 + lon;
  const float* xr = x + t * 192;
  float v0 = xr[lane], v1 = xr[lane + 64], v2 = xr[lane + 128];
  float s = v0 + v1 + v2;
  #pragma unroll
  for (int o = 32; o; o >>= 1) s += __shfl_xor(s, o);
  float mu = s * (1.0f / 192.0f);
  float d0 = v0 - mu, d1 = v1 - mu, d2 = v2 - mu;
  float q2 = d0 * d0 + d1 * d1 + d2 * d2;
  #pragma unroll
  for (int o = 32; o; o >>= 1) q2 += __shfl_xor(q2, o);
  float rstd = rsqrtf(q2 * (1.0f / 192.0f) + 1e-5f);
  bfu* orow = A1 + (size_t)r * 192;
  orow[lane]       = f2bf(d0 * rstd * g[lane]       + be[lane]);
  orow[lane + 64]  = f2bf(d1 * rstd * g[lane + 64]  + be[lane + 64]);
  orow[lane + 128] = f2bf(d2 * rstd * g[lane + 128] + be[lane + 128]);
}

// --- LN2 (natural rows) -> bf16 --------------------------------------------
__global__ __launch_bounds__(256) void ln2_kernel(
    const float* __restrict__ xin, const float* __restrict__ g,
    const float* __restrict__ be, bfu* __restrict__ yout) {
  int wv = threadIdx.x >> 6, lane = threadIdx.x & 63;
  size_t r = (size_t)blockIdx.x * 4 + wv;
  const float* xr = xin + r * 192;
  float v0 = xr[lane], v1 = xr[lane + 64], v2 = xr[lane + 128];
  float s = v0 + v1 + v2;
  #pragma unroll
  for (int o = 32; o; o >>= 1) s += __shfl_xor(s, o);
  float mu = s * (1.0f / 192.0f);
  float d0 = v0 - mu, d1 = v1 - mu, d2 = v2 - mu;
  float q2 = d0 * d0 + d1 * d1 + d2 * d2;
  #pragma unroll
  for (int o = 32; o; o >>= 1) q2 += __shfl_xor(q2, o);
  float rstd = rsqrtf(q2 * (1.0f / 192.0f) + 1e-5f);
  bfu* orow = yout + r * 192;
  orow[lane]       = f2bf(d0 * rstd * g[lane]       + be[lane]);
  orow[lane + 64]  = f2bf(d1 * rstd * g[lane + 64]  + be[lane + 64]);
  orow[lane + 128] = f2bf(d2 * rstd * g[lane + 128] + be[lane + 128]);
}

// --- MFMA GEMM: block tile 256 rows x 96 cols, 4 waves (wave = 64x96) ------
// A: bf16 [M][K] row-major. BT: bf16 [N][K] (i.e. W^T). fp32 accumulate.
// Weight tile (96 x 192-K-chunk) staged in LDS, +16B row pad (stride 200
// shorts -> 2-way LDS aliasing only, which is free). A streamed from global.
// Per k-step/wave: 4 global 16B loads + 6 ds_read_b128 + 24 MFMA.
// mode 0: qkv scatter (+bias) -> q,k,v bf16 [b][h][w][144][32]
// mode 1: proj (+bias) + un-window/un-roll + residual(aux=x) -> fp32 out0
// mode 2: fc1 (+bias) + exact GELU -> bf16 h [row][768]
// mode 3: fc2 (+bias) + residual(aux=x1) -> fp32 out0
__global__ __launch_bounds__(256) void gemm_kernel(
    const bfu* __restrict__ A, const bfu* __restrict__ BT,
    const float* __restrict__ bias, int K, int mode,
    const float* aux, void* out0, void* out1, void* out2) {
  __shared__ __align__(16) short Bs[96 * 200];   // 38.4 KB
  const int tid = threadIdx.x;
  const int wv = tid >> 6, lane = tid & 63;
  const int r16 = lane & 15, quad = lane >> 4;
  const int n0 = blockIdx.x * 96;
  const int m0 = blockIdx.y * 256 + wv * 64;

  floatx4 acc[4][6];
  #pragma unroll
  for (int s = 0; s < 4; ++s)
    #pragma unroll
    for (int j = 0; j < 6; ++j) acc[s][j] = (floatx4){0.f, 0.f, 0.f, 0.f};

  const short* Arow[4];
  #pragma unroll
  for (int s = 0; s < 4; ++s)
    Arow[s] = (const short*)A + (size_t)(m0 + s * 16 + r16) * K + quad * 8;
  const short* Bsrc = (const short*)BT + (size_t)n0 * K;

  for (int kc = 0; kc < K; kc += 192) {
    __syncthreads();
    // cooperative B-chunk load: 96 rows x 192 shorts = 2304 x 16B
    for (int i = tid; i < 2304; i += 256) {
      int row = i / 24, c16 = (i % 24) * 8;
      *(short8*)(Bs + row * 200 + c16) =
          *(const short8*)(Bsrc + (size_t)row * K + kc + c16);
    }
    __syncthreads();
    #pragma unroll
    for (int ks = 0; ks < 6; ++ks) {
      const int k = kc + ks * 32;
      short8 a[4], b[6];
      #pragma unroll
      for (int s = 0; s < 4; ++s) a[s] = *(const short8*)(Arow[s] + k);
      #pragma unroll
      for (int j = 0; j < 6; ++j)
        b[j] = *(const short8*)(Bs + (j * 16 + r16) * 200 + ks * 32 + quad * 8);
      #pragma unroll
      for (int s = 0; s < 4; ++s)
        #pragma unroll
        for (int j = 0; j < 6; ++j)
          acc[s][j] =
              __builtin_amdgcn_mfma_f32_16x16x32_bf16(a[s], b[j], acc[s][j], 0, 0, 0);
    }
  }

  // epilogue
  #pragma unroll
  for (int s = 0; s < 4; ++s) {
    const int row0 = m0 + s * 16 + quad * 4;
    #pragma unroll
    for (int j = 0; j < 6; ++j) {
      int col = n0 + j * 16 + r16;
      float bia = bias[col];
      #pragma unroll
      for (int i = 0; i < 4; ++i) {
        int row = row0 + i;
        float val = acc[s][j][i] + bia;
        if (mode == 0) {
          int n = row % 144, w = (row / 144) & 63, bb = row / 9216;
          int three = col / 192, head = (col % 192) >> 5, dd = col & 31;
          bfu* dst = (bfu*)(three == 0 ? out0 : (three == 1 ? out1 : out2));
          dst[(size_t)((bb * 6 + head) * 64 + w) * 4608 + n * 32 + dd] = f2bf(val);
        } else if (mode == 1) {
          int n = row % 144, w = (row / 144) & 63, bb = row / 9216;
          int ip = w >> 4, il = w & 15;
          int p1 = n / 72, rem = n % 72, l1 = rem / 12, o1 = rem % 12;
          int pl = ip * 2 + p1 + 1;   if (pl >= 8) pl -= 8;
          int lat = il * 6 + l1 + 3;  if (lat >= 96) lat -= 96;
          int lon = bb * 12 + o1 + 6; if (lon >= 180) lon -= 180;
          size_t t = (size_t)(pl * 96 + lat) * 180 + lon;
          ((float*)out0)[t * 192 + col] = aux[t * 192 + col] + val;
        } else if (mode == 2) {
          float ge = 0.5f * val * (1.0f + erff(val * 0.70710678118654752f));
          ((bfu*)out0)[(size_t)row * 768 + col] = f2bf(ge);
        } else {
          size_t idx = (size_t)row * 192 + col;
          ((float*)out0)[idx] = aux[idx] + val;
        }
      }
    }
  }
}

// --- windowed attention: one block per (b,h,w) ------------------------------
__global__ __launch_bounds__(256) void attn_kernel(
    const bfu* __restrict__ qg_, const bfu* __restrict__ kg_,
    const bfu* __restrict__ vg_, const bfu* __restrict__ biasp,
    bfu* __restrict__ aout) {
  __shared__ __align__(16) bfu VTs[32 * 168];   // V^T, padded
  __shared__ __align__(16) bfu Ss[144 * 160];   // logits -> P (bf16)
  __shared__ unsigned char regs[144];           // shift-mask region ids

  const int w = blockIdx.x, h = blockIdx.y, b = blockIdx.z;
  const int tid = threadIdx.x;
  const size_t base = (size_t)((b * 6 + h) * 64 + w) * 4608;
  const bfu* qg = qg_ + base;
  const bfu* kg = kg_ + base;

  if (tid < 144) {
    int n = tid;
    int p1 = n / 72, rem = n % 72, l1 = rem / 12, o1 = rem % 12;
    int ip = w >> 4, il = w & 15;
    int pl = ip * 2 + p1, lat = il * 6 + l1, lon = b * 12 + o1;
    int rp = pl < 6 ? 0 : (pl < 7 ? 1 : 2);
    int rl = lat < 90 ? 0 : (lat < 93 ? 1 : 2);
    int ro = lon < 174 ? 0 : 1;
    regs[n] = (unsigned char)(rp * 9 + rl * 3 + ro);
  }
  {
    const unsigned int* vg = (const unsigned int*)(vg_ + base);
    for (int i = tid; i < 2304; i += 256) {      // 144*32 bf16 = 2304 dwords
      unsigned int pv = vg[i];
      int m = i >> 4, d0 = (i & 15) * 2;
      VTs[d0 * 168 + m]       = (bfu)(pv & 0xffffu);
      VTs[(d0 + 1) * 168 + m] = (bfu)(pv >> 16);
    }
    for (int i = tid; i < 512; i += 256)         // zero pad cols 144..159
      VTs[(i >> 4) * 168 + 144 + (i & 15)] = 0;
  }
  __syncthreads();

  const int wv = tid >> 6, lane = tid & 63, r16 = lane & 15, quad = lane >> 4;
  const bfu* bp = biasp + (size_t)((h * 64 + w) * 144) * 144;

  // S = (Q*scale) K^T + bias + mask : 81 16x16 tiles, one MFMA each (k=32)
  for (int t = wv; t < 81; t += 4) {
    int tn = t / 9, tm = t % 9;
    short8 a  = *(const short8*)(qg + (tn * 16 + r16) * 32 + quad * 8);
    short8 bo = *(const short8*)(kg + (tm * 16 + r16) * 32 + quad * 8);
    floatx4 z = (floatx4){0.f, 0.f, 0.f, 0.f};
    floatx4 d = __builtin_amdgcn_mfma_f32_16x16x32_bf16(a, bo, z, 0, 0, 0);
    int m = tm * 16 + r16;
    unsigned char rm = regs[m];
    #pragma unroll
    for (int i = 0; i < 4; ++i) {
      int n = tn * 16 + quad * 4 + i;
      float val = d[i] * 0.17677669529663687f + bf2f(bp[(size_t)n * 144 + m]);
      if (regs[n] != rm) val -= 100.0f;
      Ss[n * 160 + m] = f2bf(val);
    }
  }
  __syncthreads();

  // softmax: wave per row (144 cols)
  for (int rr = wv; rr < 144; rr += 4) {
    float v0 = bf2f(Ss[rr * 160 + lane]);
    float v1 = bf2f(Ss[rr * 160 + 64 + lane]);
    float v2 = (lane < 16) ? bf2f(Ss[rr * 160 + 128 + lane]) : -1e30f;
    float mx = fmaxf(fmaxf(v0, v1), v2);
    #pragma unroll
    for (int o = 32; o; o >>= 1) mx = fmaxf(mx, __shfl_xor(mx, o));
    float e0 = __expf(v0 - mx), e1 = __expf(v1 - mx);
    float e2 = (lane < 16) ? __expf(v2 - mx) : 0.0f;
    float s = e0 + e1 + e2;
    #pragma unroll
    for (int o = 32; o; o >>= 1) s += __shfl_xor(s, o);
    float inv = 1.0f / s;
    Ss[rr * 160 + lane]      = f2bf(e0 * inv);
    Ss[rr * 160 + 64 + lane] = f2bf(e1 * inv);
    if (lane < 16)      Ss[rr * 160 + 128 + lane] = f2bf(e2 * inv);
    else if (lane < 32) Ss[rr * 160 + 128 + lane] = 0;  // zero pad 144..159
  }
  __syncthreads();

  // O = P V : 9 n-tiles x 2 d-tiles, k over 160 (padded) in 5 steps
  const size_t obase = (size_t)((b * 64 + w) * 144) * 192 + h * 32;
  for (int t = wv; t < 18; t += 4) {
    int tn = t / 2, td = t % 2;
    floatx4 acc = (floatx4){0.f, 0.f, 0.f, 0.f};
    #pragma unroll
    for (int km = 0; km < 5; ++km) {
      short8 a  = *(const short8*)(Ss  + (tn * 16 + r16) * 160 + km * 32 + quad * 8);
      short8 bo = *(const short8*)(VTs + (td * 16 + r16) * 168 + km * 32 + quad * 8);
      acc = __builtin_amdgcn_mfma_f32_16x16x32_bf16(a, bo, acc, 0, 0, 0);
    }
    int dd = td * 16 + r16;
    #pragma unroll
    for (int i = 0; i < 4; ++i) {
      int n = tn * 16 + quad * 4 + i;
      aout[obase + (size_t)n * 192 + dd] = f2bf(acc[i]);
    }
  }
}

// ---------------------------------------------------------------------------
extern "C" void kernel_launch(void* const* d_in, const int* in_sizes, int n_in,
                              void* d_out, int out_size, void* d_ws, size_t ws_size,
                              hipStream_t stream) {
  (void)in_sizes; (void)n_in; (void)out_size; (void)ws_size;
  const float* x     = (const float*)d_in[0];
  const float* n1g   = (const float*)d_in[1];
  const float* n1b   = (const float*)d_in[2];
  const float* qkvw  = (const float*)d_in[3];
  const float* qkvb  = (const float*)d_in[4];
  const float* tbl   = (const float*)d_in[5];
  const float* projw = (const float*)d_in[6];
  const float* projb = (const float*)d_in[7];
  const float* n2g   = (const float*)d_in[8];
  const float* n2b   = (const float*)d_in[9];
  const float* fc1w  = (const float*)d_in[10];
  const float* fc1b  = (const float*)d_in[11];
  const float* fc2w  = (const float*)d_in[12];
  const float* fc2b  = (const float*)d_in[13];

  char* ws = (char*)d_ws;
  // ws layout (bytes); peak ~282 MB
  bfu* wt_qkv   = (bfu*)(ws + 0);          //  576x192
  bfu* wt_proj  = (bfu*)(ws + 221184);     //  192x192
  bfu* wt_fc1   = (bfu*)(ws + 294912);     //  768x192
  bfu* wt_fc2   = (bfu*)(ws + 589824);     //  192x768
  bfu* bias_pre = (bfu*)(ws + 884736);     //  6*64*144*144
  bfu* A1       = (bfu*)(ws + 16809984);   //  138240x192  (A1 / attn_out / y2)
  bfu* qb       = (bfu*)(ws + 69894144);   //  q
  bfu* kb       = (bfu*)(ws + 122978304);  //  k
  bfu* vb       = (bfu*)(ws + 176062464);  //  v
  bfu* hb       = qb;                      //  h reuses q/k/v (138240x768)
  float* out    = (float*)d_out;           //  doubles as x1 buffer

  wt_kernel<<<432, 256, 0, stream>>>(qkvw, wt_qkv, 192, 576);
  wt_kernel<<<144, 256, 0, stream>>>(projw, wt_proj, 192, 192);
  wt_kernel<<<576, 256, 0, stream>>>(fc1w, wt_fc1, 192, 768);
  wt_kernel<<<576, 256, 0, stream>>>(fc2w, wt_fc2, 768, 192);
  bias_prep_kernel<<<31104, 256, 0, stream>>>(tbl, bias_pre);
  ln1_kernel<<<34560, 256, 0, stream>>>(x, n1g, n1b, A1);
  gemm_kernel<<<dim3(6, 540), 256, 0, stream>>>(A1, wt_qkv, qkvb, 192, 0,
                                                nullptr, qb, kb, vb);
  attn_kernel<<<dim3(64, 6, 15), 256, 0, stream>>>(qb, kb, vb, bias_pre, A1);
  gemm_kernel<<<dim3(2, 540), 256, 0, stream>>>(A1, wt_proj, projb, 192, 1,
                                                x, out, nullptr, nullptr);
  ln2_kernel<<<34560, 256, 0, stream>>>(out, n2g, n2b, A1);
  gemm_kernel<<<dim3(8, 540), 256, 0, stream>>>(A1, wt_fc1, fc1b, 192, 2,
                                                nullptr, hb, nullptr, nullptr);
  gemm_kernel<<<dim3(2, 540), 256, 0, stream>>>(hb, wt_fc2, fc2b, 768, 3,
                                                out, out, nullptr, nullptr);
}

// Round 3
// 1972.284 us; speedup vs baseline: 1.0518x; 1.0518x over previous
//
#include <hip/hip_runtime.h>

// ---------------------------------------------------------------------------
// Earth-specific transformer block (Pangu/swin style) for MI355X gfx950.
// DIM=192, HEADS=6 (d=32), RES=(8,96,180), WIN=(2,6,12), SHIFT=(1,3,6), MLP=4x
// All GEMMs in bf16 MFMA (16x16x32), fp32 accumulate. Output fp32.
// R1: GEMM with LDS-staged weight tile, wave tile 64x96.
// R2: attn rewritten — stride-164 S tile (conflict-free epilogue stores),
//     V pre-transposed in qkv epilogue (no LDS transpose), bias+mask moved
//     to softmax phase, Q pre-scaled, 3 blocks/CU.
// ---------------------------------------------------------------------------

typedef __attribute__((ext_vector_type(8))) short short8;
typedef __attribute__((ext_vector_type(4))) short short4v;
typedef __attribute__((ext_vector_type(4))) float floatx4;
typedef unsigned short bfu;   // raw bf16 bits

__device__ __forceinline__ bfu f2bf(float f) {
  unsigned int u = __builtin_bit_cast(unsigned int, f);
  u += 0x7fffu + ((u >> 16) & 1u);        // round-to-nearest-even
  return (bfu)(u >> 16);
}
__device__ __forceinline__ float bf2f(bfu s) {
  return __builtin_bit_cast(float, (unsigned int)s << 16);
}

// --- transpose fp32 (K x N) -> bf16 (N x K) --------------------------------
__global__ void wt_kernel(const float* __restrict__ src, bfu* __restrict__ dst,
                          int K, int N) {
  int idx = blockIdx.x * 256 + threadIdx.x;
  if (idx >= K * N) return;
  int k = idx / N, n = idx % N;
  dst[(size_t)n * K + k] = f2bf(src[idx]);
}

// --- precompute bias[h][w][n][m] (bf16) from bias_table via EPI ------------
__global__ void bias_prep_kernel(const float* __restrict__ table,
                                 bfu* __restrict__ out) {
  size_t idx = (size_t)blockIdx.x * 256 + threadIdx.x;
  if (idx >= 7962624) return;                    // 6*64*144*144
  int m = (int)(idx % 144);
  int n = (int)((idx / 144) % 144);
  int w = (int)((idx / 20736) % 64);
  int h = (int)(idx / 1327104);
  int p1 = n / 72, l1 = (n / 12) % 6, o1 = n % 12;
  int p2 = m / 72, l2 = (m / 12) % 6, o2 = m % 12;
  int ep = 828 * (p1 + 2 * p2) + 23 * (l1 + 6 * l2) + (o1 - o2 + 11);
  out[idx] = f2bf(table[(size_t)(ep * 64 + w) * 6 + h]);
}

// --- zero the m=144..159 pad columns of the transposed V buffer ------------
__global__ void vpad_kernel(unsigned int* __restrict__ vbw) {
  int tid = threadIdx.x;
  int dd = tid >> 3, c = tid & 7;
  vbw[(size_t)blockIdx.x * 2560 + dd * 80 + 72 + c] = 0;
}

// --- LN1 + roll(-shift) + window-partition gather -> bf16 A1 ---------------
__global__ __launch_bounds__(256) void ln1_kernel(
    const float* __restrict__ x, const float* __restrict__ g,
    const float* __restrict__ be, bfu* __restrict__ A1) {
  int wv = threadIdx.x >> 6, lane = threadIdx.x & 63;
  int r = blockIdx.x * 4 + wv;
  int n = r % 144, w = (r / 144) & 63, bb = r / 9216;
  int ip = w >> 4, il = w & 15;
  int p1 = n / 72, rem = n % 72, l1 = rem / 12, o1 = rem % 12;
  int pl = ip * 2 + p1 + 1;   if (pl >= 8) pl -= 8;     // rolled pos + shift
  int lat = il * 6 + l1 + 3;  if (lat >= 96) lat -= 96;
  int lon = bb * 12 + o1 + 6; if (lon >= 180) lon -= 180;
  size_t t = (size_t)(pl * 96 + lat) * 180 + lon;
  const float* xr = x + t * 192;
  float v0 = xr[lane], v1 = xr[lane + 64], v2 = xr[lane + 128];
  float s = v0 + v1 + v2;
  #pragma unroll
  for (int o = 32; o; o >>= 1) s += __shfl_xor(s, o);
  float mu = s * (1.0f / 192.0f);
  float d0 = v0 - mu, d1 = v1 - mu, d2 = v2 - mu;
  float q2 = d0 * d0 + d1 * d1 + d2 * d2;
  #pragma unroll
  for (int o = 32; o; o >>= 1) q2 += __shfl_xor(q2, o);
  float rstd = rsqrtf(q2 * (1.0f / 192.0f) + 1e-5f);
  bfu* orow = A1 + (size_t)r * 192;
  orow[lane]       = f2bf(d0 * rstd * g[lane]       + be[lane]);
  orow[lane + 64]  = f2bf(d1 * rstd * g[lane + 64]  + be[lane + 64]);
  orow[lane + 128] = f2bf(d2 * rstd * g[lane + 128] + be[lane + 128]);
}

// --- LN2 (natural rows) -> bf16 --------------------------------------------
__global__ __launch_bounds__(256) void ln2_kernel(
    const float* __restrict__ xin, const float* __restrict__ g,
    const float* __restrict__ be, bfu* __restrict__ yout) {
  int wv = threadIdx.x >> 6, lane = threadIdx.x & 63;
  size_t r = (size_t)blockIdx.x * 4 + wv;
  const float* xr = xin + r * 192;
  float v0 = xr[lane], v1 = xr[lane + 64], v2 = xr[lane + 128];
  float s = v0 + v1 + v2;
  #pragma unroll
  for (int o = 32; o; o >>= 1) s += __shfl_xor(s, o);
  float mu = s * (1.0f / 192.0f);
  float d0 = v0 - mu, d1 = v1 - mu, d2 = v2 - mu;
  float q2 = d0 * d0 + d1 * d1 + d2 * d2;
  #pragma unroll
  for (int o = 32; o; o >>= 1) q2 += __shfl_xor(q2, o);
  float rstd = rsqrtf(q2 * (1.0f / 192.0f) + 1e-5f);
  bfu* orow = yout + r * 192;
  orow[lane]       = f2bf(d0 * rstd * g[lane]       + be[lane]);
  orow[lane + 64]  = f2bf(d1 * rstd * g[lane + 64]  + be[lane + 64]);
  orow[lane + 128] = f2bf(d2 * rstd * g[lane + 128] + be[lane + 128]);
}

// --- MFMA GEMM: block tile 256 rows x 96 cols, 4 waves (wave = 64x96) ------
// mode 0: qkv scatter (+bias): q pre-scaled -> [win][n][32]; k -> [win][n][32];
//         v TRANSPOSED -> [win][dd][160] (pad cols zeroed by vpad_kernel)
// mode 1: proj (+bias) + un-window/un-roll + residual(aux=x) -> fp32 out0
// mode 2: fc1 (+bias) + exact GELU -> bf16 h [row][768]
// mode 3: fc2 (+bias) + residual(aux=x1) -> fp32 out0
__global__ __launch_bounds__(256) void gemm_kernel(
    const bfu* __restrict__ A, const bfu* __restrict__ BT,
    const float* __restrict__ bias, int K, int mode,
    const float* aux, void* out0, void* out1, void* out2) {
  __shared__ __align__(16) short Bs[96 * 200];   // 38.4 KB
  const int tid = threadIdx.x;
  const int wv = tid >> 6, lane = tid & 63;
  const int r16 = lane & 15, quad = lane >> 4;
  const int n0 = blockIdx.x * 96;
  const int m0 = blockIdx.y * 256 + wv * 64;

  floatx4 acc[4][6];
  #pragma unroll
  for (int s = 0; s < 4; ++s)
    #pragma unroll
    for (int j = 0; j < 6; ++j) acc[s][j] = (floatx4){0.f, 0.f, 0.f, 0.f};

  const short* Arow[4];
  #pragma unroll
  for (int s = 0; s < 4; ++s)
    Arow[s] = (const short*)A + (size_t)(m0 + s * 16 + r16) * K + quad * 8;
  const short* Bsrc = (const short*)BT + (size_t)n0 * K;

  for (int kc = 0; kc < K; kc += 192) {
    __syncthreads();
    // cooperative B-chunk load: 96 rows x 192 shorts = 2304 x 16B
    for (int i = tid; i < 2304; i += 256) {
      int row = i / 24, c16 = (i % 24) * 8;
      *(short8*)(Bs + row * 200 + c16) =
          *(const short8*)(Bsrc + (size_t)row * K + kc + c16);
    }
    __syncthreads();
    #pragma unroll
    for (int ks = 0; ks < 6; ++ks) {
      const int k = kc + ks * 32;
      short8 a[4], b[6];
      #pragma unroll
      for (int s = 0; s < 4; ++s) a[s] = *(const short8*)(Arow[s] + k);
      #pragma unroll
      for (int j = 0; j < 6; ++j)
        b[j] = *(const short8*)(Bs + (j * 16 + r16) * 200 + ks * 32 + quad * 8);
      #pragma unroll
      for (int s = 0; s < 4; ++s)
        #pragma unroll
        for (int j = 0; j < 6; ++j)
          acc[s][j] =
              __builtin_amdgcn_mfma_f32_16x16x32_bf16(a[s], b[j], acc[s][j], 0, 0, 0);
    }
  }

  // epilogue
  #pragma unroll
  for (int s = 0; s < 4; ++s) {
    const int row0 = m0 + s * 16 + quad * 4;
    #pragma unroll
    for (int j = 0; j < 6; ++j) {
      int col = n0 + j * 16 + r16;
      float bia = bias[col];
      #pragma unroll
      for (int i = 0; i < 4; ++i) {
        int row = row0 + i;
        float val = acc[s][j][i] + bia;
        if (mode == 0) {
          int n = row % 144, w = (row / 144) & 63, bb = row / 9216;
          int three = col / 192, head = (col % 192) >> 5, dd = col & 31;
          size_t win = (size_t)(bb * 6 + head) * 64 + w;
          if (three == 0) {          // q, pre-scaled by 1/sqrt(32)
            ((bfu*)out0)[win * 4608 + n * 32 + dd] =
                f2bf(val * 0.17677669529663687f);
          } else if (three == 1) {   // k
            ((bfu*)out1)[win * 4608 + n * 32 + dd] = f2bf(val);
          } else {                   // v, transposed [dd][m], stride 160
            ((bfu*)out2)[win * 5120 + dd * 160 + n] = f2bf(val);
          }
        } else if (mode == 1) {
          int n = row % 144, w = (row / 144) & 63, bb = row / 9216;
          int ip = w >> 4, il = w & 15;
          int p1 = n / 72, rem = n % 72, l1 = rem / 12, o1 = rem % 12;
          int pl = ip * 2 + p1 + 1;   if (pl >= 8) pl -= 8;
          int lat = il * 6 + l1 + 3;  if (lat >= 96) lat -= 96;
          int lon = bb * 12 + o1 + 6; if (lon >= 180) lon -= 180;
          size_t t = (size_t)(pl * 96 + lat) * 180 + lon;
          ((float*)out0)[t * 192 + col] = aux[t * 192 + col] + val;
        } else if (mode == 2) {
          float ge = 0.5f * val * (1.0f + erff(val * 0.70710678118654752f));
          ((bfu*)out0)[(size_t)row * 768 + col] = f2bf(ge);
        } else {
          size_t idx = (size_t)row * 192 + col;
          ((float*)out0)[idx] = aux[idx] + val;
        }
      }
    }
  }
}

// --- windowed attention: one block per (b,h,w) ------------------------------
// Q pre-scaled; V^T read from global (pre-transposed, m padded to 160).
// S tile in LDS at stride 164 shorts (82 dwords): epilogue stores 2-way only;
// PV A-frags as 8B ds_read_b64 pairs (8B-aligned by construction).
__global__ __launch_bounds__(256) void attn_kernel(
    const bfu* __restrict__ qg_, const bfu* __restrict__ kg_,
    const bfu* __restrict__ vg_, const bfu* __restrict__ biasp,
    bfu* __restrict__ aout) {
  __shared__ __align__(16) bfu Ss[144 * 164];   // 47.2 KB
  __shared__ unsigned char regs[144];           // shift-mask region ids

  const int w = blockIdx.x, h = blockIdx.y, b = blockIdx.z;
  const int tid = threadIdx.x;
  const int wv = tid >> 6, lane = tid & 63, r16 = lane & 15, quad = lane >> 4;
  const size_t win = (size_t)((b * 6 + h) * 64 + w);
  const bfu* qg = qg_ + win * 4608;
  const bfu* kg = kg_ + win * 4608;
  const bfu* vt = vg_ + win * 5120;
  const bfu* bp = biasp + (size_t)(h * 64 + w) * 20736;

  if (tid < 144) {
    int n = tid;
    int p1 = n / 72, rem = n % 72, l1 = rem / 12, o1 = rem % 12;
    int ip = w >> 4, il = w & 15;
    int pl = ip * 2 + p1, lat = il * 6 + l1, lon = b * 12 + o1;
    int rp = pl < 6 ? 0 : (pl < 7 ? 1 : 2);
    int rl = lat < 90 ? 0 : (lat < 93 ? 1 : 2);
    int ro = lon < 174 ? 0 : 1;
    regs[n] = (unsigned char)(rp * 9 + rl * 3 + ro);
  }

  // Phase 1: S = Q K^T (Q pre-scaled). 81 tiles, fixed-trip loop for unroll.
  #pragma unroll 3
  for (int u = 0; u < 21; ++u) {
    int t = wv * 21 + u;
    if (t < 81) {
      int tn = t / 9, tm = t % 9;
      short8 a  = *(const short8*)(qg + (tn * 16 + r16) * 32 + quad * 8);
      short8 bo = *(const short8*)(kg + (tm * 16 + r16) * 32 + quad * 8);
      floatx4 z = (floatx4){0.f, 0.f, 0.f, 0.f};
      floatx4 d = __builtin_amdgcn_mfma_f32_16x16x32_bf16(a, bo, z, 0, 0, 0);
      int m = tm * 16 + r16;
      #pragma unroll
      for (int i = 0; i < 4; ++i)
        Ss[(tn * 16 + quad * 4 + i) * 164 + m] = f2bf(d[i]);
    }
  }
  __syncthreads();

  // Phase 2: softmax + bias + mask. 16 rows/iter (row = 16-lane group),
  // 9 cols per lane, 4-step shfl reductions within the 16-lane group.
  for (int rb = 0; rb < 9; ++rb) {
    int rr = rb * 16 + wv * 4 + quad;
    unsigned char rgn = regs[rr];
    const bfu* srow = Ss + rr * 164;
    const bfu* brow = bp + rr * 144;
    float v[9];
    float mx = -1e30f;
    #pragma unroll
    for (int j = 0; j < 9; ++j) {
      int c = r16 + 16 * j;
      float s = bf2f(srow[c]) + bf2f(brow[c]);
      if (regs[c] != rgn) s -= 100.0f;
      v[j] = s;
      mx = fmaxf(mx, s);
    }
    #pragma unroll
    for (int o = 8; o; o >>= 1) mx = fmaxf(mx, __shfl_xor(mx, o));
    float sum = 0.f;
    #pragma unroll
    for (int j = 0; j < 9; ++j) { v[j] = __expf(v[j] - mx); sum += v[j]; }
    #pragma unroll
    for (int o = 8; o; o >>= 1) sum += __shfl_xor(sum, o);
    float inv = 1.0f / sum;
    bfu* wrow = Ss + rr * 164;
    #pragma unroll
    for (int j = 0; j < 9; ++j) wrow[r16 + 16 * j] = f2bf(v[j] * inv);
    wrow[144 + r16] = 0;                       // zero pad cols 144..159
  }
  __syncthreads();

  // Phase 3: O = P V. B-frags (V^T) hoisted from global, reused across tn.
  short8 bfr[2][5];
  #pragma unroll
  for (int td = 0; td < 2; ++td)
    #pragma unroll
    for (int km = 0; km < 5; ++km)
      bfr[td][km] =
          *(const short8*)(vt + (td * 16 + r16) * 160 + km * 32 + quad * 8);

  const size_t obase = (size_t)((b * 64 + w) * 144) * 192 + h * 32;
  #pragma unroll
  for (int u = 0; u < 5; ++u) {
    int t = wv * 5 + u;
    if (t < 18) {
      int tn = t >> 1, td = t & 1;
      floatx4 acc = (floatx4){0.f, 0.f, 0.f, 0.f};
      #pragma unroll
      for (int km = 0; km < 5; ++km) {
        const bfu* ap = Ss + (tn * 16 + r16) * 164 + km * 32 + quad * 8;
        short8 a;
        *(short4v*)&a       = *(const short4v*)ap;        // 8B ds_read_b64
        *((short4v*)&a + 1) = *(const short4v*)(ap + 4);  // 8B ds_read_b64
        acc = __builtin_amdgcn_mfma_f32_16x16x32_bf16(a, bfr[td][km], acc, 0, 0, 0);
      }
      int dd = td * 16 + r16;
      #pragma unroll
      for (int i = 0; i < 4; ++i) {
        int n = tn * 16 + quad * 4 + i;
        aout[obase + (size_t)n * 192 + dd] = f2bf(acc[i]);
      }
    }
  }
}

// ---------------------------------------------------------------------------
extern "C" void kernel_launch(void* const* d_in, const int* in_sizes, int n_in,
                              void* d_out, int out_size, void* d_ws, size_t ws_size,
                              hipStream_t stream) {
  (void)in_sizes; (void)n_in; (void)out_size; (void)ws_size;
  const float* x     = (const float*)d_in[0];
  const float* n1g   = (const float*)d_in[1];
  const float* n1b   = (const float*)d_in[2];
  const float* qkvw  = (const float*)d_in[3];
  const float* qkvb  = (const float*)d_in[4];
  const float* tbl   = (const float*)d_in[5];
  const float* projw = (const float*)d_in[6];
  const float* projb = (const float*)d_in[7];
  const float* n2g   = (const float*)d_in[8];
  const float* n2b   = (const float*)d_in[9];
  const float* fc1w  = (const float*)d_in[10];
  const float* fc1b  = (const float*)d_in[11];
  const float* fc2w  = (const float*)d_in[12];
  const float* fc2b  = (const float*)d_in[13];

  char* ws = (char*)d_ws;
  // ws layout (bytes); peak ~282 MB (hb reuses q/k/v region)
  bfu* wt_qkv   = (bfu*)(ws + 0);          //  576x192
  bfu* wt_proj  = (bfu*)(ws + 221184);     //  192x192
  bfu* wt_fc1   = (bfu*)(ws + 294912);     //  768x192
  bfu* wt_fc2   = (bfu*)(ws + 589824);     //  192x768
  bfu* bias_pre = (bfu*)(ws + 884736);     //  6*64*144*144
  bfu* A1       = (bfu*)(ws + 16809984);   //  138240x192  (A1 / attn_out / y2)
  bfu* qb       = (bfu*)(ws + 69894144);   //  q [5760][144][32]
  bfu* kb       = (bfu*)(ws + 122978304);  //  k [5760][144][32]
  bfu* vb       = (bfu*)(ws + 176062464);  //  v^T [5760][32][160]
  bfu* hb       = qb;                      //  h reuses q/k/v (138240x768)
  float* out    = (float*)d_out;           //  doubles as x1 buffer

  wt_kernel<<<432, 256, 0, stream>>>(qkvw, wt_qkv, 192, 576);
  wt_kernel<<<144, 256, 0, stream>>>(projw, wt_proj, 192, 192);
  wt_kernel<<<576, 256, 0, stream>>>(fc1w, wt_fc1, 192, 768);
  wt_kernel<<<576, 256, 0, stream>>>(fc2w, wt_fc2, 768, 192);
  bias_prep_kernel<<<31104, 256, 0, stream>>>(tbl, bias_pre);
  vpad_kernel<<<5760, 256, 0, stream>>>((unsigned int*)vb);
  ln1_kernel<<<34560, 256, 0, stream>>>(x, n1g, n1b, A1);
  gemm_kernel<<<dim3(6, 540), 256, 0, stream>>>(A1, wt_qkv, qkvb, 192, 0,
                                                nullptr, qb, kb, vb);
  attn_kernel<<<dim3(64, 6, 15), 256, 0, stream>>>(qb, kb, vb, bias_pre, A1);
  gemm_kernel<<<dim3(2, 540), 256, 0, stream>>>(A1, wt_proj, projb, 192, 1,
                                                x, out, nullptr, nullptr);
  ln2_kernel<<<34560, 256, 0, stream>>>(out, n2g, n2b, A1);
  gemm_kernel<<<dim3(8, 540), 256, 0, stream>>>(A1, wt_fc1, fc1b, 192, 2,
                                                nullptr, hb, nullptr, nullptr);
  gemm_kernel<<<dim3(2, 540), 256, 0, stream>>>(hb, wt_fc2, fc2b, 768, 3,
                                                out, out, nullptr, nullptr);
}